// Round 7
// baseline (2156.468 us; speedup 1.0000x reference)
//
#include <hip/hip_runtime.h>
#include <math.h>

#define NOUTK 1024
#define PHK   512
#define HID   24
#define G4    96
#define LSTEPS 32
#define BATCH 8192
#define EPB   16

// Dynamic LDS: 69,568 B -> 2 blocks/CU (139 KB of 160 KB), 32 waves/CU = 100%
// occupancy. R6's 119 KB (both w_lin halves resident) forced 1 block/CU; its
// 47% occupancy left the 7-barrier serial phase chain unhidden (VALUBusy 35%).
// Active half only, restaged per step from L2 (w_lin = 96 KB, L2-resident).
struct SmemD {
  float  stg[HID][64][8];    // active w_lin half [k][chunk][col]       49152 B
  float  whhT[HID][G4];      // w_hh transposed [k][row]                 9216 B
  float  blin[NOUTK];        // b_lin f32 (both halves)                  4096 B
  float  bihs[G4], bhhs[G4]; //                                           768 B
  double hsh[EPB][25];       // h state f64 (pad 25 -> conflict-free)    3200 B
  double scr[8][EPB];        // max/sum partials + candr alias           1024 B
  double tots[8][EPB];       // per-slice prob totals                    1024 B
  double Msh[EPB], invSm[EPB], ush[EPB], r0sh[EPB];                  //   512 B
  int    candj[8][EPB];      //                                           512 B
  int    actsh[EPB];         // previous action (-1 = zeros one-hot)       64 B
};

__device__ __forceinline__ float bf2f(unsigned short v) {
  union { unsigned u; float f; } x; x.u = ((unsigned)v) << 16; return x.f;
}
__device__ __forceinline__ unsigned short f2bf(float f) {
  unsigned u = __float_as_uint(f);
  unsigned r = 0x7FFFu + ((u >> 16) & 1u);
  return (unsigned short)((u + r) >> 16);
}
__device__ __forceinline__ float bfsnap(float f) { return bf2f(f2bf(f)); }

// One-time w_ih transpose into d_ws: wT[a*96+row] = wih[row*1024+a].
// The per-step one-hot gather then reads 96 CONTIGUOUS floats (6 cache lines,
// coalesced across lanes) instead of 96 scattered 64-B lines with 4 KB
// stride -- R6's FETCH_SIZE (1.4 GB/launch) was exactly that gather missing
// L2 every step, at L3 latency on the phase-L critical path.
__global__ void transpose_wih(const float* __restrict__ wih, float* __restrict__ wT) {
  const int idx = blockIdx.x * 256 + threadIdx.x;    // 98304 total
  const int a = idx / G4, row = idx % G4;
  wT[idx] = wih[row * NOUTK + a];                    // coalesced write
}

__global__ void __launch_bounds__(1024)
policy_kernel(const float* __restrict__ wihf,  const float* __restrict__ whhf,
              const float* __restrict__ bihf,  const float* __restrict__ bhhf,
              const float* __restrict__ wlinf, const float* __restrict__ blinf,
              const float* __restrict__ uf,    float* __restrict__ outg,
              const float* __restrict__ wT) {
  extern __shared__ char smraw[];
  SmemD* sm = (SmemD*)smraw;
  const int tid  = threadIdx.x;
  const int wave = tid >> 6;                // 16 waves; wave w owns element w
  const int lane = tid & 63;
  const int s    = wave & 7;                // slice: 64 active cols
  const int eg   = (wave >> 3) << 3;        // element group base (0 or 8)
  const int le   = lane & 7;                // element within group
  const int jl   = lane >> 3;               // 8-col chunk within slice
  const int eG   = eg + le;                 // element this thread computes for
  const int geL  = blockIdx.x * EPB + wave; // owner's global batch element
  const int jgl0 = s * 64 + jl * 8;         // active-local col of r=0
  const int c    = s * 8 + jl;              // stg chunk
  const int useT = (wT != nullptr);

  // ---------------- one-time staging ----------------
  for (int i = tid; i < G4 * HID; i += 1024) {
    const int row = i / HID, k = i % HID;   // coalesced global read
    sm->whhT[k][row] = whhf[i];
  }
  sm->blin[tid] = blinf[tid];
  if (tid < G4) { sm->bihs[tid] = bihf[tid]; sm->bhhs[tid] = bhhf[tid]; }
  if (tid < EPB * 25) ((double*)sm->hsh)[tid] = 0.0;
  if (tid < EPB) sm->actsh[tid] = -1;

  // w_lin restage: thread pair (2 threads/row, 3 float4 each = 48 B halves).
  // Stash is stride-1 per k-plane: banks (l>>1)%32, 2 lanes/bank = free.
  const int rrow = tid >> 1;                // row within active half (0..511)
  const int q3   = tid & 1;                 // which 12-k half of the row
  float4 pf[3];
  {
    const float4* rp = (const float4*)(wlinf + rrow * HID + q3 * 12);  // t=0 even
    #pragma unroll
    for (int q = 0; q < 3; ++q) pf[q] = rp[q];
  }

  double creg = 0.0;                        // c state: lanes<24 of owner wave
  __syncthreads();

  for (int t = 0; t < LSTEPS; ++t) {
    const int odd  = t & 1;
    const int base = odd ? PHK : 0;

    // ---- stash prefetched w_lin half to LDS; prefetch t+1's half ----
    #pragma unroll
    for (int q = 0; q < 3; ++q) {
      const float4 v = pf[q];
      const int k0 = q3 * 12 + q * 4;
      sm->stg[k0 + 0][rrow >> 3][rrow & 7] = v.x;
      sm->stg[k0 + 1][rrow >> 3][rrow & 7] = v.y;
      sm->stg[k0 + 2][rrow >> 3][rrow & 7] = v.z;
      sm->stg[k0 + 3][rrow >> 3][rrow & 7] = v.w;
    }
    {
      const float4* rp = (const float4*)
          (wlinf + (((t + 1) & 1) * PHK + rrow) * HID + q3 * 12);
      #pragma unroll
      for (int q = 0; q < 3; ++q) pf[q] = rp[q];
    }
    if (lane == 32) sm->ush[wave] = (double)uf[t * BATCH + geL];

    // ---------------- phase L: LSTM cell (owner wave, lanes 0..23) -------
    if (lane < HID) {
      const int a = sm->actsh[wave];
      double g0, g1, g2, g3;
#define GATE(Q, GOUT)                                                        \
      { const int row = (Q) * HID + lane;                                    \
        const double colA = (a >= 0)                                         \
            ? (double)(useT ? wT[a * G4 + row] : wihf[row * NOUTK + a])      \
            : 0.0;                                                           \
        double mv = 0.0;                                                     \
        _Pragma("unroll")                                                    \
        for (int k = 0; k < HID; ++k)                                        \
          mv = fma(sm->hsh[wave][k], (double)sm->whhT[k][row], mv);          \
        GOUT = ((colA + (double)sm->bihs[row]) + mv) + (double)sm->bhhs[row]; }
      GATE(0, g0) GATE(1, g1) GATE(2, g2) GATE(3, g3)
#undef GATE
      const double ig = 1.0 / (1.0 + exp(-g0));
      const double fg = 1.0 / (1.0 + exp(-g1));
      const double gv = tanh(g2);
      const double og = 1.0 / (1.0 + exp(-g3));
      creg = fg * creg + ig * gv;
      sm->hsh[wave][lane] = og * tanh(creg);
    }
    __syncthreads();                                  // b1

    // ---------------- phase G: active-half logits (8 cols/thread, f64) ---
    double z0 = 0.0, z1 = 0.0, z2 = 0.0, z3 = 0.0,
           z4 = 0.0, z5 = 0.0, z6 = 0.0, z7 = 0.0;
    for (int k = 0; k < HID; ++k) {
      const double hv = sm->hsh[eG][k];
      const float4 wa = *(const float4*)&sm->stg[k][c][0];
      const float4 wb = *(const float4*)&sm->stg[k][c][4];
      z0 = fma(hv, (double)wa.x, z0); z1 = fma(hv, (double)wa.y, z1);
      z2 = fma(hv, (double)wa.z, z2); z3 = fma(hv, (double)wa.w, z3);
      z4 = fma(hv, (double)wb.x, z4); z5 = fma(hv, (double)wb.y, z5);
      z6 = fma(hv, (double)wb.z, z6); z7 = fma(hv, (double)wb.w, z7);
    }
    {
      const float4 ba = *(const float4*)&sm->blin[base + jgl0];
      const float4 bb = *(const float4*)&sm->blin[base + jgl0 + 4];
      z0 += (double)ba.x; z1 += (double)ba.y; z2 += (double)ba.z; z3 += (double)ba.w;
      z4 += (double)bb.x; z5 += (double)bb.y; z6 += (double)bb.z; z7 += (double)bb.w;
    }

    // ---------------- softmax max over active half ----
    // (e_i/Sm is invariant to max shift and the full-softmax denominator to
    //  ~1e-16 relative — safe at f64 decision margins)
    double pm = fmax(fmax(fmax(z0, z1), fmax(z2, z3)),
                     fmax(fmax(z4, z5), fmax(z6, z7)));
    pm = fmax(pm, __shfl_xor(pm, 8));
    pm = fmax(pm, __shfl_xor(pm, 16));
    pm = fmax(pm, __shfl_xor(pm, 32));
    if (jl == 0) sm->scr[s][eG] = pm;
    __syncthreads();                                  // b2
    if (lane < 8) {
      double v = sm->scr[lane][wave];
      v = fmax(v, __shfl_xor(v, 1));
      v = fmax(v, __shfl_xor(v, 2));
      v = fmax(v, __shfl_xor(v, 4));
      if (lane == 0) sm->Msh[wave] = v;
    }
    __syncthreads();                                  // b3

    // ---------------- exp (in place) + masked-sum Sm -> inv ----
    const double Me = sm->Msh[eG];
    z0 = exp(z0 - Me); z1 = exp(z1 - Me); z2 = exp(z2 - Me); z3 = exp(z3 - Me);
    z4 = exp(z4 - Me); z5 = exp(z5 - Me); z6 = exp(z6 - Me); z7 = exp(z7 - Me);
    double ps = ((((((z0 + z1) + z2) + z3) + z4) + z5) + z6) + z7;
    ps += __shfl_xor(ps, 8);
    ps += __shfl_xor(ps, 16);
    ps += __shfl_xor(ps, 32);
    if (jl == 0) sm->scr[s][eG] = ps;
    __syncthreads();                                  // b4
    if (lane < 8) {
      double v = sm->scr[lane][wave];
      v += __shfl_xor(v, 1);
      v += __shfl_xor(v, 2);
      v += __shfl_xor(v, 4);
      if (lane == 0) sm->invSm[wave] = 1.0 / v;
    }
    __syncthreads();                                  // b5

    // ---------------- rr = e/Sm (in place), blocked prefix ----
    const double inv = sm->invSm[eG];
    z0 *= inv; z1 *= inv; z2 *= inv; z3 *= inv;
    z4 *= inv; z5 *= inv; z6 *= inv; z7 *= inv;
    const double p0 = z0,      p1 = p0 + z1, p2 = p1 + z2, p3 = p2 + z3,
                 p4 = p3 + z4, p5 = p4 + z5, p6 = p5 + z6, p7 = p6 + z7;
    double exbase = 0.0, acc = 0.0;
    #pragma unroll
    for (int q2 = 0; q2 < 8; ++q2) {
      const double tq = __shfl(p7, q2 * 8 + le);
      if (q2 == jl) exbase = acc;
      acc += tq;
    }
    if (jl == 0) sm->tots[s][eG] = acc;
    if (s == 0 && lane < 8) sm->r0sh[eG] = z0;
    __syncthreads();                                  // b6

    // ---------------- crossing search ----
    double sb = exbase;
    for (int i = 0; i < s; ++i) sb += sm->tots[i][eG];
    const double ue = sm->ush[eG];
    int jloc = 0x7FFFFFFF; double rsel = 0.0;
#define CROSS(R, PR, ZR)                                                     \
    { const double C = sb + PR;                                              \
      if (jloc == 0x7FFFFFFF && C > ue) { jloc = jgl0 + (R); rsel = ZR; } }
    CROSS(0, p0, z0) CROSS(1, p1, z1) CROSS(2, p2, z2) CROSS(3, p3, z3)
    CROSS(4, p4, z4) CROSS(5, p5, z5) CROSS(6, p6, z6) CROSS(7, p7, z7)
#undef CROSS
    { int oj = __shfl_xor(jloc, 8);  double orr = __shfl_xor(rsel, 8);  if (oj < jloc) { jloc = oj; rsel = orr; } }
    { int oj = __shfl_xor(jloc, 16); double orr = __shfl_xor(rsel, 16); if (oj < jloc) { jloc = oj; rsel = orr; } }
    { int oj = __shfl_xor(jloc, 32); double orr = __shfl_xor(rsel, 32); if (oj < jloc) { jloc = oj; rsel = orr; } }
    if (jl == 0) { sm->candj[s][eG] = jloc; sm->scr[s][eG] = rsel; }
    __syncthreads();                                  // b7

    // ---------------- owner: combine slices, emit ----
    // (no trailing barrier: stash(t+1) touches only stg, last read pre-b2;
    //  b1(t+1) fences everything else)
    if (lane < 8) {
      int cj = sm->candj[lane][wave]; double cr = sm->scr[lane][wave];
      { int oj = __shfl_xor(cj, 1); double orr = __shfl_xor(cr, 1); if (oj < cj) { cj = oj; cr = orr; } }
      { int oj = __shfl_xor(cj, 2); double orr = __shfl_xor(cr, 2); if (oj < cj) { cj = oj; cr = orr; } }
      { int oj = __shfl_xor(cj, 4); double orr = __shfl_xor(cr, 4); if (oj < cj) { cj = oj; cr = orr; } }
      if (lane == 0) {
        int actg; double p;
        if (cj == 0x7FFFFFFF) {               // cumsum never exceeded u:
          actg = 0;                           // np.argmax(all False) == 0
          p = odd ? 0.0 : sm->r0sh[wave];     // out[0] (masked -> 0 on odd)
        } else {
          actg = base + cj; p = cr;
        }
        sm->actsh[wave] = actg;
        const int io = geL * LSTEPS + t;
        outg[io]                  = bfsnap((float)p);
        outg[BATCH * LSTEPS + io] = bfsnap((float)actg);
      }
    }
  }
}

extern "C" void kernel_launch(void* const* d_in, const int* in_sizes, int n_in,
                              void* d_out, int out_size, void* d_ws, size_t ws_size,
                              hipStream_t stream) {
  (void)in_sizes; (void)n_in; (void)out_size;
  const float* wihf = (const float*)d_in[0];
  float* wT = nullptr;
  if (ws_size >= (size_t)(G4 * NOUTK * 4)) {
    wT = (float*)d_ws;
    transpose_wih<<<G4 * NOUTK / 256, 256, 0, stream>>>(wihf, wT);
  }
  hipFuncSetAttribute((const void*)policy_kernel,
                      hipFuncAttributeMaxDynamicSharedMemorySize,
                      (int)sizeof(SmemD));
  policy_kernel<<<BATCH / EPB, 1024, sizeof(SmemD), stream>>>(
      wihf, (const float*)d_in[1], (const float*)d_in[2],
      (const float*)d_in[3], (const float*)d_in[4], (const float*)d_in[5],
      (const float*)d_in[6], (float*)d_out, wT);
}

// Round 8
// 2067.074 us; speedup vs baseline: 1.0432x; 1.0432x over previous
//
#include <hip/hip_runtime.h>
#include <math.h>

#define NOUTK 1024
#define PHK   512
#define HID   24
#define G4    96
#define LSTEPS 32
#define BATCH 8192
#define EPB   16

// Dynamic LDS: 118,720 B (1 block/CU, 16 waves). Both w_lin halves resident
// => zero per-step staging, zero staging registers. R7's restage+prefetch
// added ~12 registers inside a 64-VGPR allocation and WRITE_SIZE doubled to
// 2 GB (spills) -- this version targets a ~45-VGPR peak live set instead.
struct SmemD {
  float  stg[HID][128][8];   // w_lin, BOTH halves [k][chunk][col]      98304 B
  float  whhT[HID][G4];      // w_hh transposed [k][row]                 9216 B
  float  blin[NOUTK];        // b_lin f32                                4096 B
  float  bihs[G4], bhhs[G4]; //                                           768 B
  double hsh[EPB][25];       // h state f64 (pad 25 -> conflict-free)    3200 B
  double scr[8][EPB];        // max/sum partials + candr alias           1024 B
  double tots[8][EPB];       // per-slice prob totals                    1024 B
  double Msh[EPB], invSm[EPB], ush[EPB], r0sh[EPB];                  //   512 B
  int    candj[8][EPB];      //                                           512 B
  int    actsh[EPB];         // previous action (-1 = zeros one-hot)       64 B
};

__device__ __forceinline__ float bf2f(unsigned short v) {
  union { unsigned u; float f; } x; x.u = ((unsigned)v) << 16; return x.f;
}
__device__ __forceinline__ unsigned short f2bf(float f) {
  unsigned u = __float_as_uint(f);
  unsigned r = 0x7FFFu + ((u >> 16) & 1u);
  return (unsigned short)((u + r) >> 16);
}
__device__ __forceinline__ float bfsnap(float f) { return bf2f(f2bf(f)); }

// One-time w_ih transpose into d_ws: wT[a*96+row] = wih[row*1024+a].
// Per-step one-hot gather becomes 96 contiguous floats (coalesced across the
// 24 lanes) instead of 96 lines at 4 KB stride (R6: 1.4 GB/launch of FETCH).
__global__ void transpose_wih(const float* __restrict__ wih, float* __restrict__ wT) {
  const int idx = blockIdx.x * 256 + threadIdx.x;    // 98304 total
  const int a = idx / G4, row = idx % G4;
  wT[idx] = wih[row * NOUTK + a];                    // coalesced write
}

__global__ void __launch_bounds__(1024)
policy_kernel(const float* __restrict__ wihf,  const float* __restrict__ whhf,
              const float* __restrict__ bihf,  const float* __restrict__ bhhf,
              const float* __restrict__ wlinf, const float* __restrict__ blinf,
              const float* __restrict__ uf,    float* __restrict__ outg,
              const float* __restrict__ wT) {
  extern __shared__ char smraw[];
  SmemD* sm = (SmemD*)smraw;
  const int tid  = threadIdx.x;
  const int wave = tid >> 6;                // 16 waves; wave w owns element w
  const int lane = tid & 63;
  const int s    = wave & 7;                // slice: 64 active cols
  const int eg   = (wave >> 3) << 3;        // element group base (0 or 8)
  const int le   = lane & 7;                // element within group
  const int jl   = lane >> 3;               // 8-col chunk within slice
  const int eG   = eg + le;                 // element this thread computes for
  const int geL  = blockIdx.x * EPB + wave; // owner's global batch element
  const int jgl0 = s * 64 + jl * 8;         // active-local col of r=0
  const int useT = (wT != nullptr);

  // ---------------- one-time staging (both w_lin halves) ----------------
  {
    const float4* row4 = (const float4*)(wlinf + tid * HID);  // row j = tid
    #pragma unroll
    for (int q = 0; q < 6; ++q) {
      const float4 v = row4[q];
      sm->stg[q * 4 + 0][tid >> 3][tid & 7] = v.x;
      sm->stg[q * 4 + 1][tid >> 3][tid & 7] = v.y;
      sm->stg[q * 4 + 2][tid >> 3][tid & 7] = v.z;
      sm->stg[q * 4 + 3][tid >> 3][tid & 7] = v.w;
    }
  }
  for (int i = tid; i < G4 * HID; i += 1024) {
    const int row = i / HID, k = i % HID;   // coalesced global read
    sm->whhT[k][row] = whhf[i];
  }
  sm->blin[tid] = blinf[tid];
  if (tid < G4) { sm->bihs[tid] = bihf[tid]; sm->bhhs[tid] = bhhf[tid]; }
  if (tid < EPB * 25) ((double*)sm->hsh)[tid] = 0.0;
  if (tid < EPB) sm->actsh[tid] = -1;

  double creg = 0.0;                        // c state: lanes<24 of owner wave
  __syncthreads();

  for (int t = 0; t < LSTEPS; ++t) {
    const int odd  = t & 1;
    const int base = odd ? PHK : 0;
    const int c    = (base >> 3) + s * 8 + jl;   // stg chunk for this parity

    if (lane == 32) sm->ush[wave] = (double)uf[t * BATCH + geL];

    // ---------------- phase L: LSTM cell (owner wave, lanes 0..23) -------
    // Each gate is consumed by its activation immediately (<=5 f64 live).
    if (lane < HID) {
      const int a = sm->actsh[wave];
#define GATE(Q, AOUT, ACT)                                                   \
      double AOUT;                                                           \
      { const int row = (Q) * HID + lane;                                    \
        const double colA = (a >= 0)                                         \
            ? (double)(useT ? wT[a * G4 + row] : wihf[row * NOUTK + a])      \
            : 0.0;                                                           \
        double mv = 0.0;                                                     \
        _Pragma("unroll")                                                    \
        for (int k = 0; k < HID; ++k)                                        \
          mv = fma(sm->hsh[wave][k], (double)sm->whhT[k][row], mv);          \
        const double g = ((colA + (double)sm->bihs[row]) + mv)               \
                         + (double)sm->bhhs[row];                            \
        AOUT = ACT; }
      GATE(0, ig, 1.0 / (1.0 + exp(-g)))
      GATE(1, fg, 1.0 / (1.0 + exp(-g)))
      GATE(2, gv, tanh(g))
      GATE(3, og, 1.0 / (1.0 + exp(-g)))
#undef GATE
      creg = fg * creg + ig * gv;
      sm->hsh[wave][lane] = og * tanh(creg);
    }
    __syncthreads();                                  // b1

    // ---------------- phase G: active-half logits (8 cols/thread, f64) ---
    double z0 = 0.0, z1 = 0.0, z2 = 0.0, z3 = 0.0,
           z4 = 0.0, z5 = 0.0, z6 = 0.0, z7 = 0.0;
    for (int k = 0; k < HID; ++k) {
      const double hv = sm->hsh[eG][k];
      const float4 wa = *(const float4*)&sm->stg[k][c][0];
      const float4 wb = *(const float4*)&sm->stg[k][c][4];
      z0 = fma(hv, (double)wa.x, z0); z1 = fma(hv, (double)wa.y, z1);
      z2 = fma(hv, (double)wa.z, z2); z3 = fma(hv, (double)wa.w, z3);
      z4 = fma(hv, (double)wb.x, z4); z5 = fma(hv, (double)wb.y, z5);
      z6 = fma(hv, (double)wb.z, z6); z7 = fma(hv, (double)wb.w, z7);
    }
    {
      const float4 ba = *(const float4*)&sm->blin[base + jgl0];
      const float4 bb = *(const float4*)&sm->blin[base + jgl0 + 4];
      z0 += (double)ba.x; z1 += (double)ba.y; z2 += (double)ba.z; z3 += (double)ba.w;
      z4 += (double)bb.x; z5 += (double)bb.y; z6 += (double)bb.z; z7 += (double)bb.w;
    }

    // ---------------- softmax max over active half ----
    double pm = fmax(fmax(fmax(z0, z1), fmax(z2, z3)),
                     fmax(fmax(z4, z5), fmax(z6, z7)));
    pm = fmax(pm, __shfl_xor(pm, 8));
    pm = fmax(pm, __shfl_xor(pm, 16));
    pm = fmax(pm, __shfl_xor(pm, 32));
    if (jl == 0) sm->scr[s][eG] = pm;
    __syncthreads();                                  // b2
    if (lane < 8) {
      double v = sm->scr[lane][wave];
      v = fmax(v, __shfl_xor(v, 1));
      v = fmax(v, __shfl_xor(v, 2));
      v = fmax(v, __shfl_xor(v, 4));
      if (lane == 0) sm->Msh[wave] = v;
    }
    __syncthreads();                                  // b3

    // ---------------- exp (in place) + masked-sum Sm -> inv ----
    const double Me = sm->Msh[eG];
    z0 = exp(z0 - Me); z1 = exp(z1 - Me); z2 = exp(z2 - Me); z3 = exp(z3 - Me);
    z4 = exp(z4 - Me); z5 = exp(z5 - Me); z6 = exp(z6 - Me); z7 = exp(z7 - Me);
    double ps = ((((((z0 + z1) + z2) + z3) + z4) + z5) + z6) + z7;
    ps += __shfl_xor(ps, 8);
    ps += __shfl_xor(ps, 16);
    ps += __shfl_xor(ps, 32);
    if (jl == 0) sm->scr[s][eG] = ps;
    __syncthreads();                                  // b4
    if (lane < 8) {
      double v = sm->scr[lane][wave];
      v += __shfl_xor(v, 1);
      v += __shfl_xor(v, 2);
      v += __shfl_xor(v, 4);
      if (lane == 0) sm->invSm[wave] = 1.0 / v;
    }
    __syncthreads();                                  // b5

    // ---------------- rr = e/Sm (in place), chunk totals ----
    const double inv = sm->invSm[eG];
    z0 *= inv; z1 *= inv; z2 *= inv; z3 *= inv;
    z4 *= inv; z5 *= inv; z6 *= inv; z7 *= inv;
    // chunk total == pref[7] (same left-assoc order as the old p7)
    const double tch = ((((((z0 + z1) + z2) + z3) + z4) + z5) + z6) + z7;
    double exbase = 0.0, acc = 0.0;
    #pragma unroll
    for (int q2 = 0; q2 < 8; ++q2) {
      const double tq = __shfl(tch, q2 * 8 + le);
      if (q2 == jl) exbase = acc;
      acc += tq;
    }
    if (jl == 0) sm->tots[s][eG] = acc;
    if (s == 0 && lane < 8) sm->r0sh[eG] = z0;
    __syncthreads();                                  // b6

    // ---------------- crossing search (on-the-fly prefix, 1 reg) ----
    // pr replays pref[r] = pref[r-1] + z_r bit-exactly; C = sb + pr matches
    // the old sb + pref[r] association. No p0..p7 live range (16 VGPRs gone).
    double sb = exbase;
    for (int i = 0; i < s; ++i) sb += sm->tots[i][eG];
    const double ue = sm->ush[eG];
    int jloc = 0x7FFFFFFF; double rsel = 0.0;
    double pr = z0;
#define CROSS(R, ZR)                                                         \
    { const double C = sb + pr;                                              \
      if (jloc == 0x7FFFFFFF && C > ue) { jloc = jgl0 + (R); rsel = ZR; } }
    CROSS(0, z0)
    pr += z1; CROSS(1, z1)
    pr += z2; CROSS(2, z2)
    pr += z3; CROSS(3, z3)
    pr += z4; CROSS(4, z4)
    pr += z5; CROSS(5, z5)
    pr += z6; CROSS(6, z6)
    pr += z7; CROSS(7, z7)
#undef CROSS
    { int oj = __shfl_xor(jloc, 8);  double orr = __shfl_xor(rsel, 8);  if (oj < jloc) { jloc = oj; rsel = orr; } }
    { int oj = __shfl_xor(jloc, 16); double orr = __shfl_xor(rsel, 16); if (oj < jloc) { jloc = oj; rsel = orr; } }
    { int oj = __shfl_xor(jloc, 32); double orr = __shfl_xor(rsel, 32); if (oj < jloc) { jloc = oj; rsel = orr; } }
    if (jl == 0) { sm->candj[s][eG] = jloc; sm->scr[s][eG] = rsel; }
    __syncthreads();                                  // b7

    // ---------------- owner: combine slices, emit ----
    // (no trailing barrier: b1(t+1) fences every LDS reuse)
    if (lane < 8) {
      int cj = sm->candj[lane][wave]; double cr = sm->scr[lane][wave];
      { int oj = __shfl_xor(cj, 1); double orr = __shfl_xor(cr, 1); if (oj < cj) { cj = oj; cr = orr; } }
      { int oj = __shfl_xor(cj, 2); double orr = __shfl_xor(cr, 2); if (oj < cj) { cj = oj; cr = orr; } }
      { int oj = __shfl_xor(cj, 4); double orr = __shfl_xor(cr, 4); if (oj < cj) { cj = oj; cr = orr; } }
      if (lane == 0) {
        int actg; double p;
        if (cj == 0x7FFFFFFF) {               // cumsum never exceeded u:
          actg = 0;                           // np.argmax(all False) == 0
          p = odd ? 0.0 : sm->r0sh[wave];     // out[0] (masked -> 0 on odd)
        } else {
          actg = base + cj; p = cr;
        }
        sm->actsh[wave] = actg;
        const int io = geL * LSTEPS + t;
        outg[io]                  = bfsnap((float)p);
        outg[BATCH * LSTEPS + io] = bfsnap((float)actg);
      }
    }
  }
}

extern "C" void kernel_launch(void* const* d_in, const int* in_sizes, int n_in,
                              void* d_out, int out_size, void* d_ws, size_t ws_size,
                              hipStream_t stream) {
  (void)in_sizes; (void)n_in; (void)out_size;
  const float* wihf = (const float*)d_in[0];
  float* wT = nullptr;
  if (ws_size >= (size_t)(G4 * NOUTK * 4)) {
    wT = (float*)d_ws;
    transpose_wih<<<G4 * NOUTK / 256, 256, 0, stream>>>(wihf, wT);
  }
  hipFuncSetAttribute((const void*)policy_kernel,
                      hipFuncAttributeMaxDynamicSharedMemorySize,
                      (int)sizeof(SmemD));
  policy_kernel<<<BATCH / EPB, 1024, sizeof(SmemD), stream>>>(
      wihf, (const float*)d_in[1], (const float*)d_in[2],
      (const float*)d_in[3], (const float*)d_in[4], (const float*)d_in[5],
      (const float*)d_in[6], (float*)d_out, wT);
}

// Round 9
// 2027.075 us; speedup vs baseline: 1.0638x; 1.0197x over previous
//
#include <hip/hip_runtime.h>
#include <math.h>

#define NOUTK 1024
#define PHK   512
#define HID   24
#define G4    96
#define LSTEPS 32
#define BATCH 8192
#define EPB   4
#define NSL   4    // slices (waves) per element, 128 cols each

// Dynamic LDS: 113,808 B -> 1 block/CU, 16 waves (50% occ, same as R6/R8).
// KEY CHANGE vs R8: 2 cols/thread (EPB=4) => per-thread f64 working set is
// 2 doubles, peak live ~45 VGPRs. R8 held 8 z-doubles + exp temps = ~90-100
// VGPRs of pressure inside an immovable 64-VGPR allocation (f64 = 2 VGPRs
// each -- the accounting error behind R7/R8): 1.8 GB/launch of spill traffic.
struct SmemD {
  float  stg[HID][NOUTK];    // w_lin both halves [k][col]              98304 B
  float  whhT[HID][G4];      // w_hh transposed [k][row]                 9216 B
  float  blin[NOUTK];        //                                          4096 B
  float  bihs[G4], bhhs[G4]; //                                           768 B
  double hsh[EPB][25];       // h state f64                               800 B
  double scrM[NSL][EPB];     // slice maxes                               128 B
  double scrS[NSL][EPB];     // slice sums                                128 B
  double tots[NSL][EPB];     // slice prob totals                         128 B
  double candr[NSL][EPB];    // slice candidate prob                      128 B
  double ush[EPB];           //                                            32 B
  int    candj[NSL][EPB];    // slice candidate col (or INF)               64 B
  int    actsh[EPB];         // previous action (-1 = zeros one-hot)       16 B
};

__device__ __forceinline__ float bf2f(unsigned short v) {
  union { unsigned u; float f; } x; x.u = ((unsigned)v) << 16; return x.f;
}
__device__ __forceinline__ unsigned short f2bf(float f) {
  unsigned u = __float_as_uint(f);
  unsigned r = 0x7FFFu + ((u >> 16) & 1u);
  return (unsigned short)((u + r) >> 16);
}
__device__ __forceinline__ float bfsnap(float f) { return bf2f(f2bf(f)); }

// One-time w_ih transpose into d_ws: per-step one-hot gather reads 96
// contiguous floats instead of 96 lines at 4 KB stride.
__global__ void transpose_wih(const float* __restrict__ wih, float* __restrict__ wT) {
  const int idx = blockIdx.x * 256 + threadIdx.x;    // 98304 total
  const int a = idx / G4, row = idx % G4;
  wT[idx] = wih[row * NOUTK + a];                    // coalesced write
}

__global__ void __launch_bounds__(1024)
policy_kernel(const float* __restrict__ wihf,  const float* __restrict__ whhf,
              const float* __restrict__ bihf,  const float* __restrict__ bhhf,
              const float* __restrict__ wlinf, const float* __restrict__ blinf,
              const float* __restrict__ uf,    float* __restrict__ outg,
              const float* __restrict__ wT) {
  extern __shared__ char smraw[];
  SmemD* sm = (SmemD*)smraw;
  const int tid  = threadIdx.x;
  const int wave = tid >> 6;
  const int lane = tid & 63;
  const int e    = wave & 3;                // element (4 per block)
  const int s    = wave >> 2;               // slice 0..3 (128 cols each)
  const int geL  = blockIdx.x * EPB + e;    // global batch element
  const int useT = (wT != nullptr);

  // ---------------- one-time staging ----------------
  {
    const float4* row4 = (const float4*)(wlinf + tid * HID);  // w_lin row tid
    #pragma unroll
    for (int q = 0; q < 6; ++q) {
      const float4 v = row4[q];
      sm->stg[q * 4 + 0][tid] = v.x;
      sm->stg[q * 4 + 1][tid] = v.y;
      sm->stg[q * 4 + 2][tid] = v.z;
      sm->stg[q * 4 + 3][tid] = v.w;
    }
  }
  for (int i = tid; i < G4 * HID; i += 1024)
    sm->whhT[i % HID][i / HID] = whhf[i];
  sm->blin[tid] = blinf[tid];
  if (tid < G4) { sm->bihs[tid] = bihf[tid]; sm->bhhs[tid] = bhhf[tid]; }
  if (tid < EPB * 25) ((double*)sm->hsh)[tid] = 0.0;
  if (tid < EPB) sm->actsh[tid] = -1;

  double creg = 0.0;                        // c state: lanes<24 of wave e
  __syncthreads();

  for (int t = 0; t < LSTEPS; ++t) {
    const int odd  = t & 1;
    const int base = odd ? PHK : 0;

    if (s == 0 && lane == 32) sm->ush[e] = (double)uf[t * BATCH + geL];

    // -------- phase L: LSTM (wave e, lanes 0..47; 2 gates/lane) --------
    // lanes 0..23: rows j, j+24 (gates i,f); lanes 24..47: rows 48+j, 72+j
    // (gates g,o). Per-gate expressions identical to R6/R8.
    if (s == 0 && lane < 48) {
      const int a  = sm->actsh[e];
      const int rb = (lane < 24) ? lane : lane + 24;
      double aA, aB;
      {
        const int row = rb;
        const double colA = (a >= 0)
            ? (double)(useT ? wT[a * G4 + row] : wihf[row * NOUTK + a]) : 0.0;
        double mv = 0.0;
        #pragma unroll
        for (int k = 0; k < HID; ++k)
          mv = fma(sm->hsh[e][k], (double)sm->whhT[k][row], mv);
        const double g = ((colA + (double)sm->bihs[row]) + mv)
                         + (double)sm->bhhs[row];
        aA = (lane < 24) ? (1.0 / (1.0 + exp(-g))) : tanh(g);
      }
      {
        const int row = rb + 24;
        const double colA = (a >= 0)
            ? (double)(useT ? wT[a * G4 + row] : wihf[row * NOUTK + a]) : 0.0;
        double mv = 0.0;
        #pragma unroll
        for (int k = 0; k < HID; ++k)
          mv = fma(sm->hsh[e][k], (double)sm->whhT[k][row], mv);
        const double g = ((colA + (double)sm->bihs[row]) + mv)
                         + (double)sm->bhhs[row];
        aB = 1.0 / (1.0 + exp(-g));         // gates f and o are both sigmoid
      }
      const double gvx = __shfl(aA, lane + 24);   // gv for lane<24
      const double ogx = __shfl(aB, lane + 24);   // og for lane<24
      if (lane < 24) {
        creg = aB * creg + aA * gvx;              // c = f*c + i*g
        sm->hsh[e][lane] = ogx * tanh(creg);      // h = o*tanh(c)
      }
    }
    __syncthreads();                                  // b1

    // -------- phase G: logits, 2 cols/thread (f64) --------
    const int cA = base + s * 128 + lane * 2;   // global col (even)
    double z0 = 0.0, z1 = 0.0;
    #pragma unroll
    for (int k = 0; k < HID; ++k) {
      const double hv = sm->hsh[e][k];
      const float2 w = *(const float2*)&sm->stg[k][cA];
      z0 = fma(hv, (double)w.x, z0);
      z1 = fma(hv, (double)w.y, z1);
    }
    {
      const float2 b = *(const float2*)&sm->blin[cA];
      z0 += (double)b.x; z1 += (double)b.y;
    }

    // -------- softmax max (exact under reassociation) --------
    double pm = fmax(z0, z1);
    #pragma unroll
    for (int d = 1; d < 64; d <<= 1) pm = fmax(pm, __shfl_xor(pm, d));
    if (lane == 0) sm->scrM[s][e] = pm;
    __syncthreads();                                  // b2
    const double Me = fmax(fmax(sm->scrM[0][e], sm->scrM[1][e]),
                           fmax(sm->scrM[2][e], sm->scrM[3][e]));

    // -------- exp + sum (butterfly; ~1e-16 reassoc noise, safe) --------
    z0 = exp(z0 - Me); z1 = exp(z1 - Me);
    double ps = z0 + z1;
    #pragma unroll
    for (int d = 1; d < 64; d <<= 1) ps += __shfl_xor(ps, d);
    if (lane == 0) sm->scrS[s][e] = ps;
    __syncthreads();                                  // b3
    const double inv = 1.0 / (((sm->scrS[0][e] + sm->scrS[1][e])
                               + sm->scrS[2][e]) + sm->scrS[3][e]);

    // -------- normalize + lane-prefix scan --------
    z0 *= inv; z1 *= inv;
    const double tt = z0 + z1;
    double incl = tt;
    #pragma unroll
    for (int d = 1; d < 64; d <<= 1) {
      const double o = __shfl_up(incl, d);
      if (lane >= d) incl += o;
    }
    const double ex = incl - tt;            // exclusive prefix of this lane
    if (lane == 63) sm->tots[s][e] = incl;  // slice total
    const double r0loc = z0;                // prob of col `base` (s==0,lane==0)
    __syncthreads();                                  // b4

    // -------- crossing search --------
    double sb = 0.0;
    for (int i = 0; i < s; ++i) sb += sm->tots[i][e];
    const double sbase = sb + ex;
    const double ue = sm->ush[e];
    int jloc = 0x7FFFFFFF; double rsel = 0.0;
    {
      double pr = z0;
      double C = sbase + pr;
      if (C > ue) { jloc = s * 128 + lane * 2; rsel = z0; }
      pr += z1;
      C = sbase + pr;
      if (jloc == 0x7FFFFFFF && C > ue) { jloc = s * 128 + lane * 2 + 1; rsel = z1; }
    }
    #pragma unroll
    for (int d = 1; d < 64; d <<= 1) {
      const int oj = __shfl_xor(jloc, d);
      const double orr = __shfl_xor(rsel, d);
      if (oj < jloc) { jloc = oj; rsel = orr; }
    }
    if (lane == 0) { sm->candj[s][e] = jloc; sm->candr[s][e] = rsel; }
    __syncthreads();                                  // b5

    // -------- owner (wave e, lane 0): combine slices, emit --------
    // (no trailing barrier: actsh/hsh rewrites happen post-b5 by wave e and
    //  are only re-read after the next step's fences -- see R6 analysis)
    if (s == 0 && lane == 0) {
      int cj = 0x7FFFFFFF; double cr = 0.0;
      #pragma unroll
      for (int i = 0; i < NSL; ++i) {
        const int j2 = sm->candj[i][e];
        if (cj == 0x7FFFFFFF && j2 != 0x7FFFFFFF) { cj = j2; cr = sm->candr[i][e]; }
      }
      int actg; double p;
      if (cj == 0x7FFFFFFF) {               // cumsum never exceeded u:
        actg = 0;                           // np.argmax(all False) == 0
        p = odd ? 0.0 : r0loc;              // out[0] (masked -> 0 on odd)
      } else {
        actg = base + cj; p = cr;
      }
      sm->actsh[e] = actg;
      const int io = geL * LSTEPS + t;
      outg[io]                  = bfsnap((float)p);
      outg[BATCH * LSTEPS + io] = bfsnap((float)actg);
    }
  }
}

extern "C" void kernel_launch(void* const* d_in, const int* in_sizes, int n_in,
                              void* d_out, int out_size, void* d_ws, size_t ws_size,
                              hipStream_t stream) {
  (void)in_sizes; (void)n_in; (void)out_size;
  const float* wihf = (const float*)d_in[0];
  float* wT = nullptr;
  if (ws_size >= (size_t)(G4 * NOUTK * 4)) {
    wT = (float*)d_ws;
    transpose_wih<<<G4 * NOUTK / 256, 256, 0, stream>>>(wihf, wT);
  }
  hipFuncSetAttribute((const void*)policy_kernel,
                      hipFuncAttributeMaxDynamicSharedMemorySize,
                      (int)sizeof(SmemD));
  policy_kernel<<<BATCH / EPB, 1024, sizeof(SmemD), stream>>>(
      wihf, (const float*)d_in[1], (const float*)d_in[2],
      (const float*)d_in[3], (const float*)d_in[4], (const float*)d_in[5],
      (const float*)d_in[6], (float*)d_out, wT);
}